// Round 6
// baseline (6100.678 us; speedup 1.0000x reference)
//
#include <hip/hip_runtime.h>

// DeepM3Model: 200-step GRU+RK4 scan (B=1024,S=200,H=256) + head GEMM to 50000 items.
// Inputs/outputs are fp32. On-device dtype sniff retained as a safety net.
// Pipeline: sniff -> canon weights to bf16 -> dt -> gi table (item_emb@Wih^T+bih,
// fp32 preferred) -> persistent WG-local scan -> head GEMM.
//
// R6 theory: the invariant cost is the per-CU weight stream (1.4 MB/step/CU from
// L2; every CU needs all weights every step). R0-R5 proved time is insensitive to
// spills/NT/batching because each phase serializes load->wait->MFMA->barrier,
// achieving only ~45% of the per-CU VMEM return BW. Fix: one-phase-ahead register
// prefetch (phase p issues phase p+1's weight loads, computes on fragments loaded
// during phase p-1; the barrier's vmcnt drain is then free). To fit the double
// buffer (64 VGPRs) under the hard 128-reg cap (R1/R3), scan restructured to
// 16 waves x 16 cols (1024 thr), same math. Step body pair-unrolled so buffer
// roles alternate at compile time (no runtime-indexed frag arrays).

#define B_SZ   1024
#define S_LEN  200
#define HD     256
#define NITEMS 50000
#define NPAD   50048

// canonical weight block offsets (u16 elements)
#define OFF_WHH 0
#define OFF_WIH 196608
#define OFF_W1  393216
#define OFF_W2  458752
#define OFF_BHH 524288
#define OFF_BIH 525056
#define OFF_B1  525824
#define OFF_B2  526080
#define CANON_N 526336

typedef short short8 __attribute__((ext_vector_type(8)));
typedef float f32x4  __attribute__((ext_vector_type(4)));

__device__ __forceinline__ float bf2f(unsigned short u){
  unsigned v = ((unsigned)u) << 16; float f; __builtin_memcpy(&f, &v, 4); return f;
}
__device__ __forceinline__ unsigned short f2bf(float f){
  unsigned u; __builtin_memcpy(&u, &f, 4);
  u += 0x7FFFu + ((u >> 16) & 1u);            // round-to-nearest-even
  return (unsigned short)(u >> 16);
}
__device__ __forceinline__ float fsig(float x){ return 1.0f / (1.0f + __expf(-x)); }
__device__ __forceinline__ float ftanh(float x){
  float e = __expf(-2.0f * fabsf(x));
  float r = (1.0f - e) / (1.0f + e);
  return copysignf(r, x);
}
__device__ __forceinline__ f32x4 MFMA(short8 a, short8 b, f32x4 c){
  return __builtin_amdgcn_mfma_f32_16x16x32_bf16(a, b, c, 0, 0, 0);
}
// fragment-order LDS layout for a [16 rows x 256 k] bf16 plane:
// 16B unit index = kc*16 + ((row^kc)&15)  -> conflict-free b128 reads/writes
__device__ __forceinline__ int foff(int kc, int row){
  return (kc * 16 + ((row ^ kc) & 15)) * 8;  // element (short) index
}

// ---------------- dtype sniff: t sorted in [0,10]; bf16 u16 <= 0x4120 always.
__global__ void sniff_kernel(const unsigned short* __restrict__ t, int* __restrict__ flag){
  int lane = threadIdx.x & 63;
  int bad = 0;
#pragma unroll
  for (int q = 0; q < 8; ++q)
    if (t[lane * 8 + q] > 0x4200u) bad = 1;
  unsigned long long m = __ballot(bad);
  if (lane == 0) flag[0] = (m != 0ull) ? 1 : 0;
}

// ---------------- canonicalize small weights to bf16
__global__ void conv_kernel(const int* __restrict__ flag,
    const void* __restrict__ Whh, const void* __restrict__ Wih,
    const void* __restrict__ W1,  const void* __restrict__ W2,
    const void* __restrict__ bhh, const void* __restrict__ bih,
    const void* __restrict__ b1,  const void* __restrict__ b2,
    unsigned short* __restrict__ dst)
{
  int i = blockIdx.x * 256 + threadIdx.x;
  if (i >= CANON_N) return;
  int f32m = flag[0];
  const void* src; int off = i;
  if (i < OFF_WIH)      { src = Whh; off = i - OFF_WHH; }
  else if (i < OFF_W1)  { src = Wih; off = i - OFF_WIH; }
  else if (i < OFF_W2)  { src = W1;  off = i - OFF_W1; }
  else if (i < OFF_BHH) { src = W2;  off = i - OFF_W2; }
  else if (i < OFF_BIH) { src = bhh; off = i - OFF_BHH; }
  else if (i < OFF_B1)  { src = bih; off = i - OFF_BIH; }
  else if (i < OFF_B2)  { src = b1;  off = i - OFF_B1; }
  else                  { src = b2;  off = i - OFF_B2; }
  unsigned short v = f32m ? f2bf(((const float*)src)[off])
                          : ((const unsigned short*)src)[off];
  dst[i] = v;
}

// ---------------- W_head -> bf16 (4 elements per thread)
__global__ void convw_kernel(const int* __restrict__ flag,
    const void* __restrict__ Wh, unsigned short* __restrict__ dst)
{
  int i4 = blockIdx.x * 256 + threadIdx.x;
  if (i4 * 4 >= NITEMS * HD) return;
  if (flag[0]){
    f32x4 v = ((const f32x4*)Wh)[i4];
#pragma unroll
    for (int q = 0; q < 4; ++q) dst[i4 * 4 + q] = f2bf(v[q]);
  } else {
    ((unsigned long long*)dst)[i4] = ((const unsigned long long*)Wh)[i4];
  }
}

// ---------------- dt precompute
__global__ void dt_kernel(const void* __restrict__ t, const int* __restrict__ flag,
                          float* __restrict__ dt){
  int i = blockIdx.x * 256 + threadIdx.x;
  if (i >= B_SZ * S_LEN) return;
  int f32m = flag[0];
  int s = i % S_LEN;
  float tc = f32m ? ((const float*)t)[i] : bf2f(((const unsigned short*)t)[i]);
  float d = 0.0f;
  if (s < S_LEN - 1){
    float tn = f32m ? ((const float*)t)[i + 1] : bf2f(((const unsigned short*)t)[i + 1]);
    d = fmaxf(tn, tc + 1e-5f) - tc;
  }
  dt[i] = d;
}

// ---------------- G[i, j] = sum_k emb[i,k] * Wih[j,k] + bih[j]   (i<50000, j<768)
__global__ __launch_bounds__(256) void gitems_kernel(
    const void* __restrict__ emb, const unsigned short* __restrict__ canon,
    const int* __restrict__ flag, void* __restrict__ tbl, int tblf32)
{
  __shared__ __align__(16) short ap[4][4096];    // 4 row-tiles x [16x256] bf16
  const int tid = threadIdx.x;
  const int i0 = blockIdx.x * 64;
  const int n0 = blockIdx.y * 256;
  const int f32m = flag[0];
  {
    int kc = tid & 31, r8 = tid >> 5;
#pragma unroll
    for (int p = 0; p < 8; ++p){
      int row = p * 8 + r8;
      int gr = i0 + row; if (gr > NITEMS - 1) gr = NITEMS - 1;
      short8 v;
      if (f32m){
        const f32x4* src = (const f32x4*)((const float*)emb + gr * HD + kc * 8);
        f32x4 v0 = src[0], v1 = src[1];
#pragma unroll
        for (int q = 0; q < 4; ++q){ v[q] = (short)f2bf(v0[q]); v[4+q] = (short)f2bf(v1[q]); }
      } else {
        v = *(const short8*)((const unsigned short*)emb + gr * HD + kc * 8);
      }
      *(short8*)&ap[row >> 4][foff(kc, row & 15)] = v;
    }
  }
  __syncthreads();
  const int wave = tid >> 6, lane = tid & 63, col = lane & 15, quad = lane >> 4;
  const unsigned short* Wih = canon + OFF_WIH;
  const unsigned short* bih = canon + OFF_BIH;
  f32x4 zz = {0.0f, 0.0f, 0.0f, 0.0f};
  f32x4 acc[4][4];
#pragma unroll
  for (int rt = 0; rt < 4; ++rt)
#pragma unroll
    for (int ct = 0; ct < 4; ++ct) acc[rt][ct] = zz;

#pragma unroll
  for (int ks = 0; ks < 8; ++ks){
    short8 bf[4];
#pragma unroll
    for (int ct = 0; ct < 4; ++ct){
      int n = n0 + wave * 64 + ct * 16 + col;
      bf[ct] = *(const short8*)(Wih + n * HD + ks * 32 + quad * 8);
    }
    int kc = ks * 4 + quad;
#pragma unroll
    for (int rt = 0; rt < 4; ++rt){
      short8 a = *(const short8*)&ap[rt][foff(kc, col)];
#pragma unroll
      for (int ct = 0; ct < 4; ++ct) acc[rt][ct] = MFMA(a, bf[ct], acc[rt][ct]);
    }
  }
  float bv[4];
#pragma unroll
  for (int ct = 0; ct < 4; ++ct) bv[ct] = bf2f(bih[n0 + wave * 64 + ct * 16 + col]);
  float* tfo = (float*)tbl; unsigned short* tbo = (unsigned short*)tbl;
#pragma unroll
  for (int rt = 0; rt < 4; ++rt)
#pragma unroll
    for (int ct = 0; ct < 4; ++ct)
#pragma unroll
      for (int r = 0; r < 4; ++r){
        int row = i0 + rt * 16 + quad * 4 + r;
        if (row < NITEMS){
          int n = n0 + wave * 64 + ct * 16 + col;
          float v = acc[rt][ct][r] + bv[ct];
          if (tblf32) tfo[row * 768 + n] = v;
          else        tbo[row * 768 + n] = (unsigned short)f2bf(v);
        }
      }
}

// ---------------- persistent scan: 64 WGs x 1024 thr (16 waves); WG owns 16 rows;
// wave owns 16 hidden cols. One-phase-ahead weight prefetch: phase p computes on
// fragments loaded during phase p-1 while issuing phase p+1's loads. The
// __syncthreads vmcnt drain then costs ~nothing (loads had a full phase in flight).

// load 8 B-fragments for this wave's 16-col slice of one 256-row weight block
#define LDW(DST, PTR) \
  _Pragma("unroll") for (int ks_ = 0; ks_ < 8; ++ks_) \
    DST[ks_] = *(const short8*)((PTR) + ks_ * 32 + quad * 8);

// 16 MFMAs: hi+lo A planes (stage-0 gh)
#define MM16(ACC, W, PB) \
  _Pragma("unroll") for (int ks_ = 0; ks_ < 8; ++ks_){ \
    int kc_ = ks_ * 4 + quad; \
    short8 ahi_ = *(const short8*)&bufhi[PB][foff(kc_, col)]; \
    short8 alo_ = *(const short8*)&buflo[PB][foff(kc_, col)]; \
    ACC = MFMA(ahi_, W[ks_], ACC); \
    ACC = MFMA(alo_, W[ks_], ACC); }

// u-stage: read bufhi[1-PB], write tanh to bufhi[PB]; prefetch next weights
#define RK4U(CUR, PRE, PPTR, PB) { \
  LDW(PRE, PPTR); \
  __builtin_amdgcn_sched_barrier(0); \
  f32x4 ua_ = {b1c, b1c, b1c, b1c}; \
  _Pragma("unroll") for (int ks_ = 0; ks_ < 8; ++ks_){ \
    int kc_ = ks_ * 4 + quad; \
    short8 a_ = *(const short8*)&bufhi[1-(PB)][foff(kc_, col)]; \
    ua_ = MFMA(a_, CUR[ks_], ua_); } \
  _Pragma("unroll") for (int r_ = 0; r_ < 4; ++r_){ \
    int row_ = quad * 4 + r_; \
    bufhi[PB][foff(cw >> 3, row_) + (cw & 7)] = (short)f2bf(ftanh(ua_[r_])); } }

// k-stage: read bufhi[PB], write y/h to bufhi[1-PB] (+buflo at J==3)
#define RK4K(CUR, PRE, PPTR, PB, J) { \
  LDW(PRE, PPTR); \
  __builtin_amdgcn_sched_barrier(0); \
  f32x4 ka_ = {b2c, b2c, b2c, b2c}; \
  _Pragma("unroll") for (int ks_ = 0; ks_ < 8; ++ks_){ \
    int kc_ = ks_ * 4 + quad; \
    short8 a_ = *(const short8*)&bufhi[PB][foff(kc_, col)]; \
    ka_ = MFMA(a_, CUR[ks_], ka_); } \
  _Pragma("unroll") for (int r_ = 0; r_ < 4; ++r_){ \
    int row_ = quad * 4 + r_; \
    float kv_ = ka_[r_]; \
    if ((J) == 0) ksum[r_] = kv_; \
    else if ((J) == 3) ksum[r_] += kv_; \
    else ksum[r_] += 2.0f * kv_; \
    if ((J) < 3){ \
      float y_ = hg[r_] + (((J) == 2) ? dtr[r_] : 0.5f * dtr[r_]) * kv_; \
      bufhi[1-(PB)][foff(cw >> 3, row_) + (cw & 7)] = (short)f2bf(y_); \
    } else { \
      float hn_ = hg[r_] + (dtr[r_] * (1.0f / 6.0f)) * ksum[r_]; \
      h[r_] = hn_; \
      unsigned short hh_ = f2bf(hn_); \
      float fh_ = bf2f(hh_); \
      bufhi[1-(PB)][foff(cw >> 3, row_) + (cw & 7)] = (short)hh_; \
      buflo[1-(PB)][foff(cw >> 3, row_) + (cw & 7)] = (short)f2bf(hn_ - fh_); } } }

// full step; WA holds the R-block fragments on entry; on exit the other buffer
// holds next step's R-block fragments.
#define STEP(WA, WB, PB, S) { \
  float dtr[4]; \
  _Pragma("unroll") for (int r_ = 0; r_ < 4; ++r_) \
    dtr[r_] = dtall[(quad * 4 + r_) * S_LEN + (S)]; \
  f32x4 aR = {0,0,0,0}, aZ = {0,0,0,0}, aN = {0,0,0,0}; \
  float gRv[4], gZv[4], gNv[4]; \
  /* P0: prefetch Z, issue gi gathers, MFMA R */ \
  LDW(WB, pZ); \
  _Pragma("unroll") for (int r_ = 0; r_ < 4; ++r_){ \
    long base_ = (long)xl[(quad * 4 + r_) * S_LEN + (S)] * 768; \
    if (tblf32){ \
      gRv[r_] = __builtin_nontemporal_load(tf + base_ + cw); \
      gZv[r_] = __builtin_nontemporal_load(tf + base_ + 256 + cw); \
      gNv[r_] = __builtin_nontemporal_load(tf + base_ + 512 + cw); \
    } else { \
      gRv[r_] = bf2f(__builtin_nontemporal_load(tb + base_ + cw)); \
      gZv[r_] = bf2f(__builtin_nontemporal_load(tb + base_ + 256 + cw)); \
      gNv[r_] = bf2f(__builtin_nontemporal_load(tb + base_ + 512 + cw)); } } \
  __builtin_amdgcn_sched_barrier(0); \
  MM16(aR, WA, PB); \
  /* P1: prefetch N, MFMA Z */ \
  LDW(WA, pN); \
  __builtin_amdgcn_sched_barrier(0); \
  MM16(aZ, WB, PB); \
  /* P2: prefetch W1, MFMA N */ \
  LDW(WB, p1); \
  __builtin_amdgcn_sched_barrier(0); \
  MM16(aN, WA, PB); \
  /* gates + GRU update */ \
  float hg[4], ksum[4]; \
  _Pragma("unroll") for (int r_ = 0; r_ < 4; ++r_){ \
    int row_ = quad * 4 + r_; \
    float rr_ = fsig(aR[r_] + gRv[r_] + bR); \
    float z__ = fsig(aZ[r_] + gZv[r_] + bZ); \
    float nn_ = ftanh(gNv[r_] + rr_ * (aN[r_] + bN)); \
    float hgv_ = (1.0f - z__) * nn_ + z__ * h[r_]; \
    hg[r_] = hgv_; \
    bufhi[1-(PB)][foff(cw >> 3, row_) + (cw & 7)] = (short)f2bf(hgv_); } \
  __syncthreads(); \
  RK4U(WB, WA, p2, PB);      __syncthreads(); \
  RK4K(WA, WB, p1, PB, 0);   __syncthreads(); \
  RK4U(WB, WA, p2, PB);      __syncthreads(); \
  RK4K(WA, WB, p1, PB, 1);   __syncthreads(); \
  RK4U(WB, WA, p2, PB);      __syncthreads(); \
  RK4K(WA, WB, p1, PB, 2);   __syncthreads(); \
  RK4U(WB, WA, p2, PB);      __syncthreads(); \
  RK4K(WA, WB, pR, PB, 3);   __syncthreads(); }   /* last k prefetches next R */

__global__ __launch_bounds__(1024)
void scan_kernel(
    const int* __restrict__ x, const float* __restrict__ dtp,
    const unsigned short* __restrict__ canon,
    const void* __restrict__ tbl, int tblf32,
    float* __restrict__ hstate)
{
  __shared__ __align__(16) short bufhi[2][4096];   // ping-pong A planes (bf16 hi)
  __shared__ __align__(16) short buflo[2][4096];   // lo plane (h state only)
  __shared__ __align__(16) int   xl[16 * S_LEN];   // item indices, staged once
  __shared__ __align__(16) float dtall[16 * S_LEN];// dt, staged once

  const int tid  = threadIdx.x;
  const int wave = tid >> 6;          // 0..15
  const int lane = tid & 63;
  const int col  = lane & 15;
  const int quad = lane >> 4;
  const int r0   = blockIdx.x * 16;   // batch rows owned by this WG
  const int cw   = wave * 16 + col;   // this lane's hidden column (0..255)

  const unsigned short* Whh = canon + OFF_WHH;
  const unsigned short* W1w = canon + OFF_W1;
  const unsigned short* W2w = canon + OFF_W2;
  const unsigned short* bhh = canon + OFF_BHH;
  const unsigned short* b1v = canon + OFF_B1;
  const unsigned short* b2v = canon + OFF_B2;

  // per-lane row pointers for this wave's 16-col weight slices
  const unsigned short* pR = Whh + (0 * HD + cw) * HD;
  const unsigned short* pZ = Whh + (1 * HD + cw) * HD;
  const unsigned short* pN = Whh + (2 * HD + cw) * HD;
  const unsigned short* p1 = W1w + cw * HD;
  const unsigned short* p2 = W2w + cw * HD;

  if (tid < 512){ // zero initial h buffer (buf 0): h0 = 0
    short8 z = {0,0,0,0,0,0,0,0};
    *(short8*)&bufhi[0][tid * 8] = z;
    *(short8*)&buflo[0][tid * 8] = z;
  }
  for (int i = tid; i < 16 * S_LEN; i += 1024){
    xl[i]    = x[r0 * S_LEN + i];
    dtall[i] = dtp[r0 * S_LEN + i];
  }

  const float bR  = bf2f(bhh[cw]);
  const float bZ  = bf2f(bhh[HD + cw]);
  const float bN  = bf2f(bhh[2 * HD + cw]);
  const float b1c = bf2f(b1v[cw]);
  const float b2c = bf2f(b2v[cw]);

  float h[4];
#pragma unroll
  for (int r = 0; r < 4; ++r) h[r] = 0.0f;

  const float* tf = (const float*)tbl;
  const unsigned short* tb = (const unsigned short*)tbl;

  short8 wA[8], wB[8];
  LDW(wA, pR);                    // prologue: R-block fragments for step 0

  __syncthreads();

  for (int s = 0; s < S_LEN; s += 2){
    STEP(wA, wB, 0, s);           // even step: pb=0, wA holds R
    STEP(wB, wA, 1, s + 1);       // odd step: pb=1, wB holds R
  }

  // store final h (fp32)
#pragma unroll
  for (int r = 0; r < 4; ++r){
    int row = quad * 4 + r;
    hstate[(r0 + row) * HD + cw] = h[r];
  }
}

// ---------------- head: out[b,n] = sum_k h[b,k]*Whead[n,k] + bhead[n]
// out dtype follows flag (fp32 normally, bf16 fallback).
__global__ __launch_bounds__(256) void head_kernel(
    const float* __restrict__ hstate,
    const unsigned short* __restrict__ Whb,   // preconverted bf16 (wbf=1) or null path
    const void* __restrict__ Wh,              // original W_head
    const void* __restrict__ bh, const int* __restrict__ flag, int wbf,
    void* __restrict__ outv)
{
  __shared__ __align__(16) short ahi[4][4096];
  __shared__ __align__(16) short alo[4][4096];
  const int tid = threadIdx.x;
  const int i0 = blockIdx.x * 64;
  const int n0 = blockIdx.y * 256;
  const int f32m = flag[0];
  {
    int kc = tid & 31, r8 = tid >> 5;
#pragma unroll
    for (int p = 0; p < 8; ++p){
      int row = p * 8 + r8;
      const float* src = hstate + (i0 + row) * HD + kc * 8;
      short8 vh, vl;
#pragma unroll
      for (int q = 0; q < 8; ++q){
        float f = src[q];
        unsigned short hb = f2bf(f);
        float fh = bf2f(hb);
        vh[q] = (short)hb; vl[q] = (short)f2bf(f - fh);
      }
      int off = foff(kc, row & 15);
      *(short8*)&ahi[row >> 4][off] = vh;
      *(short8*)&alo[row >> 4][off] = vl;
    }
  }
  __syncthreads();
  const int wave = tid >> 6, lane = tid & 63, col = lane & 15, quad = lane >> 4;
  f32x4 zz = {0.0f, 0.0f, 0.0f, 0.0f};
  f32x4 acc[4][4];
#pragma unroll
  for (int rt = 0; rt < 4; ++rt)
#pragma unroll
    for (int ct = 0; ct < 4; ++ct) acc[rt][ct] = zz;

  int nidx[4];
#pragma unroll
  for (int ct = 0; ct < 4; ++ct){
    int n = n0 + wave * 64 + ct * 16 + col;
    nidx[ct] = (n < NITEMS) ? n : (NITEMS - 1);
  }
#pragma unroll
  for (int ks = 0; ks < 8; ++ks){
    short8 bf[4];
#pragma unroll
    for (int ct = 0; ct < 4; ++ct){
      if (wbf){
        bf[ct] = *(const short8*)(Whb + nidx[ct] * HD + ks * 32 + quad * 8);
      } else if (f32m){
        const f32x4* src = (const f32x4*)((const float*)Wh + nidx[ct] * HD + ks * 32 + quad * 8);
        f32x4 v0 = src[0], v1 = src[1];
        short8 v;
#pragma unroll
        for (int q = 0; q < 4; ++q){ v[q] = (short)f2bf(v0[q]); v[4+q] = (short)f2bf(v1[q]); }
        bf[ct] = v;
      } else {
        bf[ct] = *(const short8*)((const unsigned short*)Wh + nidx[ct] * HD + ks * 32 + quad * 8);
      }
    }
    int kc = ks * 4 + quad;
#pragma unroll
    for (int rt = 0; rt < 4; ++rt){
      short8 xh = *(const short8*)&ahi[rt][foff(kc, col)];
      short8 xl2 = *(const short8*)&alo[rt][foff(kc, col)];
#pragma unroll
      for (int ct = 0; ct < 4; ++ct){
        acc[rt][ct] = MFMA(xh, bf[ct], acc[rt][ct]);
        acc[rt][ct] = MFMA(xl2, bf[ct], acc[rt][ct]);
      }
    }
  }
  float bhv[4];
#pragma unroll
  for (int ct = 0; ct < 4; ++ct)
    bhv[ct] = f32m ? ((const float*)bh)[nidx[ct]] : bf2f(((const unsigned short*)bh)[nidx[ct]]);
  float* outf = (float*)outv;
  unsigned short* outb = (unsigned short*)outv;
#pragma unroll
  for (int rt = 0; rt < 4; ++rt)
#pragma unroll
    for (int ct = 0; ct < 4; ++ct)
#pragma unroll
      for (int r = 0; r < 4; ++r){
        int row = i0 + rt * 16 + quad * 4 + r;
        int n = n0 + wave * 64 + ct * 16 + col;
        if (n < NITEMS){
          float v = acc[rt][ct][r] + bhv[ct];
          long o = (long)row * NITEMS + n;
          if (f32m) outf[o] = v;
          else      outb[o] = (unsigned short)f2bf(v);
        }
      }
}

extern "C" void kernel_launch(void* const* d_in, const int* in_sizes, int n_in,
                              void* d_out, int out_size, void* d_ws, size_t ws_size,
                              hipStream_t stream) {
  const int*  x     = (const int*)d_in[0];
  const void* t     = d_in[1];
  const void* emb   = d_in[2];
  const void* Wih   = d_in[3];
  const void* Whh   = d_in[4];
  const void* bih   = d_in[5];
  const void* bhh   = d_in[6];
  const void* W1    = d_in[7];
  const void* b1    = d_in[8];
  const void* W2    = d_in[9];
  const void* b2    = d_in[10];
  const void* Whead = d_in[11];
  const void* bhead = d_in[12];

  char* ws = (char*)d_ws;
  int*   flag   = (int*)(ws);                              // @0      (4 B)
  float* dtbuf  = (float*)(ws + 4096);                     // 819200 B
  float* hstate = (float*)(ws + (1u << 20));               // 1 MB @ +1MB
  unsigned short* canon = (unsigned short*)(ws + (2u << 20));   // ~1.01 MB @ +2MB
  unsigned short* wheadb = (unsigned short*)(ws + (4u << 20));  // 25.6 MB @ +4MB
  const size_t tbase = 32u << 20;                          // table @ +32MB
  const size_t TBL_F32  = (size_t)NPAD * 768 * 4;          // 153.7 MB
  const size_t TBL_BF16 = (size_t)NPAD * 768 * 2;          // 76.9 MB

  int wbf = (ws_size >= (32u << 20)) ? 1 : 0;
  void* tbl; int tblf32;
  if (ws_size >= tbase + TBL_F32)       { tbl = (void*)(ws + tbase); tblf32 = 1; }
  else if (ws_size >= tbase + TBL_BF16) { tbl = (void*)(ws + tbase); tblf32 = 0; }
  else                                  { tbl = (void*)d_out;        tblf32 = 0; } // d_out(204.8MB fp32) as scratch; head overwrites

  sniff_kernel<<<dim3(1), dim3(64), 0, stream>>>((const unsigned short*)t, flag);
  conv_kernel<<<dim3((CANON_N + 255) / 256), dim3(256), 0, stream>>>(
      flag, Whh, Wih, W1, W2, bhh, bih, b1, b2, canon);
  if (wbf)
    convw_kernel<<<dim3((NITEMS * HD / 4 + 255) / 256), dim3(256), 0, stream>>>(
        flag, Whead, wheadb);
  dt_kernel<<<dim3((B_SZ * S_LEN + 255) / 256), dim3(256), 0, stream>>>(t, flag, dtbuf);
  gitems_kernel<<<dim3(NPAD / 64, 3), dim3(256), 0, stream>>>(emb, canon, flag, tbl, tblf32);
  scan_kernel<<<dim3(64), dim3(1024), 0, stream>>>(x, dtbuf, canon, tbl, tblf32, hstate);
  head_kernel<<<dim3(B_SZ / 64, (NITEMS + 255) / 256), dim3(256), 0, stream>>>(
      hstate, wheadb, Whead, bhead, flag, wbf, d_out);
}

// Round 7
// 4370.472 us; speedup vs baseline: 1.3959x; 1.3959x over previous
//
#include <hip/hip_runtime.h>

// DeepM3Model: 200-step GRU+RK4 scan (B=1024,S=200,H=256) + head GEMM to 50000 items.
// Inputs/outputs are fp32. On-device dtype sniff retained as a safety net.
// Pipeline: sniff -> canon weights to bf16 -> dt -> gi table (item_emb@Wih^T+bih,
// fp32 preferred) -> persistent WG-local scan -> head GEMM.
//
// R7 theory: hard rule on this toolchain: 512-thr blocks => 128-VGPR budget
// (immovable; R1/R3/R6). Dominant cost = per-CU weight stream (1.4 MB/step);
// the W1/W2 restream (1.0 MB of it) is deletable within 128 regs:
//   - W1 resident in VGPRs (64 regs; half the old W1+W2 footprint),
//   - W2 resident in LDS (128 KB staged once, foff fragment layout ->
//     conflict-free b128 reads; LDS total 152 KB, 1 WG/CU, grid 64 < 256 CUs),
//   - Whh streamed via one 32-reg batch buffer (6 rounds x 8 loads + 16 MFMAs),
//   - x/dt read direct from global (L1 lines reused across steps).
// RK4 stages then do ZERO global loads; per-step L2 traffic 1.4 -> 0.43 MB.

#define B_SZ   1024
#define S_LEN  200
#define HD     256
#define NITEMS 50000
#define NPAD   50048

// canonical weight block offsets (u16 elements)
#define OFF_WHH 0
#define OFF_WIH 196608
#define OFF_W1  393216
#define OFF_W2  458752
#define OFF_BHH 524288
#define OFF_BIH 525056
#define OFF_B1  525824
#define OFF_B2  526080
#define CANON_N 526336

typedef short short8 __attribute__((ext_vector_type(8)));
typedef float f32x4  __attribute__((ext_vector_type(4)));

__device__ __forceinline__ float bf2f(unsigned short u){
  unsigned v = ((unsigned)u) << 16; float f; __builtin_memcpy(&f, &v, 4); return f;
}
__device__ __forceinline__ unsigned short f2bf(float f){
  unsigned u; __builtin_memcpy(&u, &f, 4);
  u += 0x7FFFu + ((u >> 16) & 1u);            // round-to-nearest-even
  return (unsigned short)(u >> 16);
}
__device__ __forceinline__ float fsig(float x){ return 1.0f / (1.0f + __expf(-x)); }
__device__ __forceinline__ float ftanh(float x){
  float e = __expf(-2.0f * fabsf(x));
  float r = (1.0f - e) / (1.0f + e);
  return copysignf(r, x);
}
__device__ __forceinline__ f32x4 MFMA(short8 a, short8 b, f32x4 c){
  return __builtin_amdgcn_mfma_f32_16x16x32_bf16(a, b, c, 0, 0, 0);
}
// fragment-order LDS layout for a [16 rows x 256 k] bf16 plane:
// 16B unit index = kc*16 + ((row^kc)&15)  -> conflict-free b128 reads/writes
__device__ __forceinline__ int foff(int kc, int row){
  return (kc * 16 + ((row ^ kc) & 15)) * 8;  // element (short) index
}

// ---------------- dtype sniff: t sorted in [0,10]; bf16 u16 <= 0x4120 always.
__global__ void sniff_kernel(const unsigned short* __restrict__ t, int* __restrict__ flag){
  int lane = threadIdx.x & 63;
  int bad = 0;
#pragma unroll
  for (int q = 0; q < 8; ++q)
    if (t[lane * 8 + q] > 0x4200u) bad = 1;
  unsigned long long m = __ballot(bad);
  if (lane == 0) flag[0] = (m != 0ull) ? 1 : 0;
}

// ---------------- canonicalize small weights to bf16
__global__ void conv_kernel(const int* __restrict__ flag,
    const void* __restrict__ Whh, const void* __restrict__ Wih,
    const void* __restrict__ W1,  const void* __restrict__ W2,
    const void* __restrict__ bhh, const void* __restrict__ bih,
    const void* __restrict__ b1,  const void* __restrict__ b2,
    unsigned short* __restrict__ dst)
{
  int i = blockIdx.x * 256 + threadIdx.x;
  if (i >= CANON_N) return;
  int f32m = flag[0];
  const void* src; int off = i;
  if (i < OFF_WIH)      { src = Whh; off = i - OFF_WHH; }
  else if (i < OFF_W1)  { src = Wih; off = i - OFF_WIH; }
  else if (i < OFF_W2)  { src = W1;  off = i - OFF_W1; }
  else if (i < OFF_BHH) { src = W2;  off = i - OFF_W2; }
  else if (i < OFF_BIH) { src = bhh; off = i - OFF_BHH; }
  else if (i < OFF_B1)  { src = bih; off = i - OFF_BIH; }
  else if (i < OFF_B2)  { src = b1;  off = i - OFF_B1; }
  else                  { src = b2;  off = i - OFF_B2; }
  unsigned short v = f32m ? f2bf(((const float*)src)[off])
                          : ((const unsigned short*)src)[off];
  dst[i] = v;
}

// ---------------- W_head -> bf16 (4 elements per thread)
__global__ void convw_kernel(const int* __restrict__ flag,
    const void* __restrict__ Wh, unsigned short* __restrict__ dst)
{
  int i4 = blockIdx.x * 256 + threadIdx.x;
  if (i4 * 4 >= NITEMS * HD) return;
  if (flag[0]){
    f32x4 v = ((const f32x4*)Wh)[i4];
#pragma unroll
    for (int q = 0; q < 4; ++q) dst[i4 * 4 + q] = f2bf(v[q]);
  } else {
    ((unsigned long long*)dst)[i4] = ((const unsigned long long*)Wh)[i4];
  }
}

// ---------------- dt precompute
__global__ void dt_kernel(const void* __restrict__ t, const int* __restrict__ flag,
                          float* __restrict__ dt){
  int i = blockIdx.x * 256 + threadIdx.x;
  if (i >= B_SZ * S_LEN) return;
  int f32m = flag[0];
  int s = i % S_LEN;
  float tc = f32m ? ((const float*)t)[i] : bf2f(((const unsigned short*)t)[i]);
  float d = 0.0f;
  if (s < S_LEN - 1){
    float tn = f32m ? ((const float*)t)[i + 1] : bf2f(((const unsigned short*)t)[i + 1]);
    d = fmaxf(tn, tc + 1e-5f) - tc;
  }
  dt[i] = d;
}

// ---------------- G[i, j] = sum_k emb[i,k] * Wih[j,k] + bih[j]   (i<50000, j<768)
__global__ __launch_bounds__(256) void gitems_kernel(
    const void* __restrict__ emb, const unsigned short* __restrict__ canon,
    const int* __restrict__ flag, void* __restrict__ tbl, int tblf32)
{
  __shared__ __align__(16) short ap[4][4096];    // 4 row-tiles x [16x256] bf16
  const int tid = threadIdx.x;
  const int i0 = blockIdx.x * 64;
  const int n0 = blockIdx.y * 256;
  const int f32m = flag[0];
  {
    int kc = tid & 31, r8 = tid >> 5;
#pragma unroll
    for (int p = 0; p < 8; ++p){
      int row = p * 8 + r8;
      int gr = i0 + row; if (gr > NITEMS - 1) gr = NITEMS - 1;
      short8 v;
      if (f32m){
        const f32x4* src = (const f32x4*)((const float*)emb + gr * HD + kc * 8);
        f32x4 v0 = src[0], v1 = src[1];
#pragma unroll
        for (int q = 0; q < 4; ++q){ v[q] = (short)f2bf(v0[q]); v[4+q] = (short)f2bf(v1[q]); }
      } else {
        v = *(const short8*)((const unsigned short*)emb + gr * HD + kc * 8);
      }
      *(short8*)&ap[row >> 4][foff(kc, row & 15)] = v;
    }
  }
  __syncthreads();
  const int wave = tid >> 6, lane = tid & 63, col = lane & 15, quad = lane >> 4;
  const unsigned short* Wih = canon + OFF_WIH;
  const unsigned short* bih = canon + OFF_BIH;
  f32x4 zz = {0.0f, 0.0f, 0.0f, 0.0f};
  f32x4 acc[4][4];
#pragma unroll
  for (int rt = 0; rt < 4; ++rt)
#pragma unroll
    for (int ct = 0; ct < 4; ++ct) acc[rt][ct] = zz;

#pragma unroll
  for (int ks = 0; ks < 8; ++ks){
    short8 bf[4];
#pragma unroll
    for (int ct = 0; ct < 4; ++ct){
      int n = n0 + wave * 64 + ct * 16 + col;
      bf[ct] = *(const short8*)(Wih + n * HD + ks * 32 + quad * 8);
    }
    int kc = ks * 4 + quad;
#pragma unroll
    for (int rt = 0; rt < 4; ++rt){
      short8 a = *(const short8*)&ap[rt][foff(kc, col)];
#pragma unroll
      for (int ct = 0; ct < 4; ++ct) acc[rt][ct] = MFMA(a, bf[ct], acc[rt][ct]);
    }
  }
  float bv[4];
#pragma unroll
  for (int ct = 0; ct < 4; ++ct) bv[ct] = bf2f(bih[n0 + wave * 64 + ct * 16 + col]);
  float* tfo = (float*)tbl; unsigned short* tbo = (unsigned short*)tbl;
#pragma unroll
  for (int rt = 0; rt < 4; ++rt)
#pragma unroll
    for (int ct = 0; ct < 4; ++ct)
#pragma unroll
      for (int r = 0; r < 4; ++r){
        int row = i0 + rt * 16 + quad * 4 + r;
        if (row < NITEMS){
          int n = n0 + wave * 64 + ct * 16 + col;
          float v = acc[rt][ct][r] + bv[ct];
          if (tblf32) tfo[row * 768 + n] = v;
          else        tbo[row * 768 + n] = (unsigned short)f2bf(v);
        }
      }
}

// ---------------- persistent scan: 64 WGs x 512 thr (8 waves); WG owns 16 rows;
// wave owns 32 hidden cols (2 tiles of 16). W1 resident in VGPRs, W2 resident in
// LDS (foff fragment layout), Whh streamed per step via one 32-reg batch buffer.
__global__ __launch_bounds__(512)
void scan_kernel(
    const int* __restrict__ x, const float* __restrict__ dtp,
    const unsigned short* __restrict__ canon,
    const void* __restrict__ tbl, int tblf32,
    float* __restrict__ hstate)
{
  __shared__ __align__(16) short bufhi[2][4096];   // ping-pong A planes (bf16 hi)
  __shared__ __align__(16) short buflo[4096];      // lo plane (h only; barrier-safe single)
  __shared__ __align__(16) short w2lds[16][4096];  // W2, 16 col-tiles in foff layout

  const int tid  = threadIdx.x;
  const int wave = tid >> 6;
  const int lane = tid & 63;
  const int col  = lane & 15;
  const int quad = lane >> 4;
  const int r0   = blockIdx.x * 16;
  const int wc0  = wave * 32;

  const unsigned short* Whh = canon + OFF_WHH;
  const unsigned short* W1w = canon + OFF_W1;
  const unsigned short* W2w = canon + OFF_W2;
  const unsigned short* bhh = canon + OFF_BHH;
  const unsigned short* b1v = canon + OFF_B1;
  const unsigned short* b2v = canon + OFF_B2;

  // stage W2 into LDS, fragment order (tile t holds cols t*16..t*16+15)
  for (int c = tid; c < 8192; c += 512){
    int kc = c & 31, row = (c >> 5) & 15, t = c >> 9;
    *(short8*)&w2lds[t][foff(kc, row)] =
        *(const short8*)(W2w + (t * 16 + row) * HD + kc * 8);
  }
  { // zero initial h planes
    short8 z = {0,0,0,0,0,0,0,0};
    *(short8*)&bufhi[0][tid * 8] = z;
    *(short8*)&buflo[tid * 8] = z;
  }

  // resident W1 fragments (64 VGPRs)
  short8 w1f[2][8];
#pragma unroll
  for (int ct = 0; ct < 2; ++ct){
    int n = wc0 + ct * 16 + col;
#pragma unroll
    for (int ks = 0; ks < 8; ++ks)
      w1f[ct][ks] = *(const short8*)(W1w + n * HD + ks * 32 + quad * 8);
  }
  float bR[2], bZ[2], bN[2], b1c[2], b2c[2];
#pragma unroll
  for (int ct = 0; ct < 2; ++ct){
    int c = wc0 + ct * 16 + col;
    bR[ct]  = bf2f(bhh[c]);          bZ[ct] = bf2f(bhh[HD + c]);
    bN[ct]  = bf2f(bhh[2 * HD + c]);
    b1c[ct] = bf2f(b1v[c]);          b2c[ct] = bf2f(b2v[c]);
  }

  float h[2][4];
#pragma unroll
  for (int ct = 0; ct < 2; ++ct)
#pragma unroll
    for (int r = 0; r < 4; ++r) h[ct][r] = 0.0f;

  const float* tf = (const float*)tbl;
  const unsigned short* tb = (const unsigned short*)tbl;

  __syncthreads();

  for (int s = 0; s < S_LEN; ++s){
    const int pb = s & 1;
    int xi[4]; float dtr[4];
#pragma unroll
    for (int r = 0; r < 4; ++r){
      int row = quad * 4 + r;
      xi[r]  = x[(r0 + row) * S_LEN + s];     // L1-resident line, reused across steps
      dtr[r] = dtp[(r0 + row) * S_LEN + s];
    }

    // ---- stage 0: gh = h @ Whh^T, per ct-tile; Whh streamed in 8-frag batches
    float hg[2][4], ksum[2][4];
#pragma unroll
    for (int ct = 0; ct < 2; ++ct){
      const int nb = wc0 + ct * 16 + col;
      f32x4 aR, aZ, aN;
      float giN[4];
      // gathers first (overlap the weight-load latency); acc pre-init
#pragma unroll
      for (int r = 0; r < 4; ++r){
        long base = (long)xi[r] * 768;
        if (tblf32){
          aR[r]  = __builtin_nontemporal_load(tf + base + nb);
          aZ[r]  = __builtin_nontemporal_load(tf + base + 256 + nb);
          giN[r] = __builtin_nontemporal_load(tf + base + 512 + nb);
        } else {
          aR[r]  = bf2f(__builtin_nontemporal_load(tb + base + nb));
          aZ[r]  = bf2f(__builtin_nontemporal_load(tb + base + 256 + nb));
          giN[r] = bf2f(__builtin_nontemporal_load(tb + base + 512 + nb));
        }
        aN[r] = 0.0f;                         // i_n separate: r gates only h-part
      }
      short8 wb[8];
#pragma unroll
      for (int g = 0; g < 3; ++g){
#pragma unroll
        for (int ks = 0; ks < 8; ++ks)
          wb[ks] = *(const short8*)(Whh + (g * HD + nb) * HD + ks * 32 + quad * 8);
        __builtin_amdgcn_sched_barrier(0);    // keep the 8-load batch together
        f32x4 acc = {0.0f, 0.0f, 0.0f, 0.0f};
#pragma unroll
        for (int ks = 0; ks < 8; ++ks){
          int kc = ks * 4 + quad;
          short8 ahi = *(const short8*)&bufhi[pb][foff(kc, col)];
          short8 alo = *(const short8*)&buflo[foff(kc, col)];
          acc = MFMA(ahi, wb[ks], acc);
          acc = MFMA(alo, wb[ks], acc);
        }
        if (g == 0)      aR += acc;
        else if (g == 1) aZ += acc;
        else             aN += acc;
      }
      // gates + GRU update for this ct
#pragma unroll
      for (int r = 0; r < 4; ++r){
        int row = quad * 4 + r;
        float rr = fsig(aR[r] + bR[ct]);
        float z_ = fsig(aZ[r] + bZ[ct]);
        float nn = ftanh(giN[r] + rr * (aN[r] + bN[ct]));
        float hgv = (1.0f - z_) * nn + z_ * h[ct][r];
        hg[ct][r] = hgv;
        bufhi[1 - pb][foff(nb >> 3, row) + (nb & 7)] = (short)f2bf(hgv);
      }
    }
    __syncthreads();                                   // barrier 1

    // ---- RK4: 4 x (u = tanh(y@W1^T+b1); k = u@W2^T+b2)
    // u: resident W1 (VGPRs); k: W2 from LDS. Zero global loads.
#pragma unroll
    for (int j = 0; j < 4; ++j){
      // u-stage: read bufhi[1-pb], write tanh to bufhi[pb]
      f32x4 ua[2];
      ua[0] = (f32x4){b1c[0], b1c[0], b1c[0], b1c[0]};
      ua[1] = (f32x4){b1c[1], b1c[1], b1c[1], b1c[1]};
#pragma unroll
      for (int ks = 0; ks < 8; ++ks){
        int kc = ks * 4 + quad;
        short8 a = *(const short8*)&bufhi[1 - pb][foff(kc, col)];
        ua[0] = MFMA(a, w1f[0][ks], ua[0]);
        ua[1] = MFMA(a, w1f[1][ks], ua[1]);
      }
#pragma unroll
      for (int ct = 0; ct < 2; ++ct)
#pragma unroll
        for (int r = 0; r < 4; ++r){
          int row = quad * 4 + r, c = wc0 + ct * 16 + col;
          bufhi[pb][foff(c >> 3, row) + (c & 7)] = (short)f2bf(ftanh(ua[ct][r]));
        }
      __syncthreads();

      // k-stage: read bufhi[pb] + W2 from LDS, write y/h to bufhi[1-pb]
      f32x4 ka[2];
      ka[0] = (f32x4){b2c[0], b2c[0], b2c[0], b2c[0]};
      ka[1] = (f32x4){b2c[1], b2c[1], b2c[1], b2c[1]};
#pragma unroll
      for (int ks = 0; ks < 8; ++ks){
        int kc = ks * 4 + quad;
        short8 a = *(const short8*)&bufhi[pb][foff(kc, col)];
        short8 w20 = *(const short8*)&w2lds[wave * 2 + 0][foff(kc, col)];
        short8 w21 = *(const short8*)&w2lds[wave * 2 + 1][foff(kc, col)];
        ka[0] = MFMA(a, w20, ka[0]);
        ka[1] = MFMA(a, w21, ka[1]);
      }
#pragma unroll
      for (int ct = 0; ct < 2; ++ct)
#pragma unroll
        for (int r = 0; r < 4; ++r){
          int row = quad * 4 + r;
          float dtv = dtr[r];
          float kv = ka[ct][r];
          int c = wc0 + ct * 16 + col;
          if (j == 0){
            ksum[ct][r] = kv;
            float y = hg[ct][r] + 0.5f * dtv * kv;
            bufhi[1 - pb][foff(c >> 3, row) + (c & 7)] = (short)f2bf(y);
          } else if (j == 1){
            ksum[ct][r] += 2.0f * kv;
            float y = hg[ct][r] + 0.5f * dtv * kv;
            bufhi[1 - pb][foff(c >> 3, row) + (c & 7)] = (short)f2bf(y);
          } else if (j == 2){
            ksum[ct][r] += 2.0f * kv;
            float y = hg[ct][r] + dtv * kv;
            bufhi[1 - pb][foff(c >> 3, row) + (c & 7)] = (short)f2bf(y);
          } else {
            ksum[ct][r] += kv;
            float hn = hg[ct][r] + (dtv * (1.0f / 6.0f)) * ksum[ct][r];
            h[ct][r] = hn;
            unsigned short hh = f2bf(hn);
            float fh = bf2f(hh);
            bufhi[1 - pb][foff(c >> 3, row) + (c & 7)] = (short)hh;
            buflo[foff(c >> 3, row) + (c & 7)] = (short)f2bf(hn - fh);
          }
        }
      __syncthreads();
    }
  }
  // store final h (fp32)
#pragma unroll
  for (int ct = 0; ct < 2; ++ct)
#pragma unroll
    for (int r = 0; r < 4; ++r){
      int row = quad * 4 + r;
      hstate[(r0 + row) * HD + wc0 + ct * 16 + col] = h[ct][r];
    }
}

// ---------------- head: out[b,n] = sum_k h[b,k]*Whead[n,k] + bhead[n]
// out dtype follows flag (fp32 normally, bf16 fallback).
__global__ __launch_bounds__(256) void head_kernel(
    const float* __restrict__ hstate,
    const unsigned short* __restrict__ Whb,   // preconverted bf16 (wbf=1) or null path
    const void* __restrict__ Wh,              // original W_head
    const void* __restrict__ bh, const int* __restrict__ flag, int wbf,
    void* __restrict__ outv)
{
  __shared__ __align__(16) short ahi[4][4096];
  __shared__ __align__(16) short alo[4][4096];
  const int tid = threadIdx.x;
  const int i0 = blockIdx.x * 64;
  const int n0 = blockIdx.y * 256;
  const int f32m = flag[0];
  {
    int kc = tid & 31, r8 = tid >> 5;
#pragma unroll
    for (int p = 0; p < 8; ++p){
      int row = p * 8 + r8;
      const float* src = hstate + (i0 + row) * HD + kc * 8;
      short8 vh, vl;
#pragma unroll
      for (int q = 0; q < 8; ++q){
        float f = src[q];
        unsigned short hb = f2bf(f);
        float fh = bf2f(hb);
        vh[q] = (short)hb; vl[q] = (short)f2bf(f - fh);
      }
      int off = foff(kc, row & 15);
      *(short8*)&ahi[row >> 4][off] = vh;
      *(short8*)&alo[row >> 4][off] = vl;
    }
  }
  __syncthreads();
  const int wave = tid >> 6, lane = tid & 63, col = lane & 15, quad = lane >> 4;
  f32x4 zz = {0.0f, 0.0f, 0.0f, 0.0f};
  f32x4 acc[4][4];
#pragma unroll
  for (int rt = 0; rt < 4; ++rt)
#pragma unroll
    for (int ct = 0; ct < 4; ++ct) acc[rt][ct] = zz;

  int nidx[4];
#pragma unroll
  for (int ct = 0; ct < 4; ++ct){
    int n = n0 + wave * 64 + ct * 16 + col;
    nidx[ct] = (n < NITEMS) ? n : (NITEMS - 1);
  }
#pragma unroll
  for (int ks = 0; ks < 8; ++ks){
    short8 bf[4];
#pragma unroll
    for (int ct = 0; ct < 4; ++ct){
      if (wbf){
        bf[ct] = *(const short8*)(Whb + nidx[ct] * HD + ks * 32 + quad * 8);
      } else if (f32m){
        const f32x4* src = (const f32x4*)((const float*)Wh + nidx[ct] * HD + ks * 32 + quad * 8);
        f32x4 v0 = src[0], v1 = src[1];
        short8 v;
#pragma unroll
        for (int q = 0; q < 4; ++q){ v[q] = (short)f2bf(v0[q]); v[4+q] = (short)f2bf(v1[q]); }
        bf[ct] = v;
      } else {
        bf[ct] = *(const short8*)((const unsigned short*)Wh + nidx[ct] * HD + ks * 32 + quad * 8);
      }
    }
    int kc = ks * 4 + quad;
#pragma unroll
    for (int rt = 0; rt < 4; ++rt){
      short8 xh = *(const short8*)&ahi[rt][foff(kc, col)];
      short8 xl2 = *(const short8*)&alo[rt][foff(kc, col)];
#pragma unroll
      for (int ct = 0; ct < 4; ++ct){
        acc[rt][ct] = MFMA(xh, bf[ct], acc[rt][ct]);
        acc[rt][ct] = MFMA(xl2, bf[ct], acc[rt][ct]);
      }
    }
  }
  float bhv[4];
#pragma unroll
  for (int ct = 0; ct < 4; ++ct)
    bhv[ct] = f32m ? ((const float*)bh)[nidx[ct]] : bf2f(((const unsigned short*)bh)[nidx[ct]]);
  float* outf = (float*)outv;
  unsigned short* outb = (unsigned short*)outv;
#pragma unroll
  for (int rt = 0; rt < 4; ++rt)
#pragma unroll
    for (int ct = 0; ct < 4; ++ct)
#pragma unroll
      for (int r = 0; r < 4; ++r){
        int row = i0 + rt * 16 + quad * 4 + r;
        int n = n0 + wave * 64 + ct * 16 + col;
        if (n < NITEMS){
          float v = acc[rt][ct][r] + bhv[ct];
          long o = (long)row * NITEMS + n;
          if (f32m) outf[o] = v;
          else      outb[o] = (unsigned short)f2bf(v);
        }
      }
}

extern "C" void kernel_launch(void* const* d_in, const int* in_sizes, int n_in,
                              void* d_out, int out_size, void* d_ws, size_t ws_size,
                              hipStream_t stream) {
  const int*  x     = (const int*)d_in[0];
  const void* t     = d_in[1];
  const void* emb   = d_in[2];
  const void* Wih   = d_in[3];
  const void* Whh   = d_in[4];
  const void* bih   = d_in[5];
  const void* bhh   = d_in[6];
  const void* W1    = d_in[7];
  const void* b1    = d_in[8];
  const void* W2    = d_in[9];
  const void* b2    = d_in[10];
  const void* Whead = d_in[11];
  const void* bhead = d_in[12];

  char* ws = (char*)d_ws;
  int*   flag   = (int*)(ws);                              // @0      (4 B)
  float* dtbuf  = (float*)(ws + 4096);                     // 819200 B
  float* hstate = (float*)(ws + (1u << 20));               // 1 MB @ +1MB
  unsigned short* canon = (unsigned short*)(ws + (2u << 20));   // ~1.01 MB @ +2MB
  unsigned short* wheadb = (unsigned short*)(ws + (4u << 20));  // 25.6 MB @ +4MB
  const size_t tbase = 32u << 20;                          // table @ +32MB
  const size_t TBL_F32  = (size_t)NPAD * 768 * 4;          // 153.7 MB
  const size_t TBL_BF16 = (size_t)NPAD * 768 * 2;          // 76.9 MB

  int wbf = (ws_size >= (32u << 20)) ? 1 : 0;
  void* tbl; int tblf32;
  if (ws_size >= tbase + TBL_F32)       { tbl = (void*)(ws + tbase); tblf32 = 1; }
  else if (ws_size >= tbase + TBL_BF16) { tbl = (void*)(ws + tbase); tblf32 = 0; }
  else                                  { tbl = (void*)d_out;        tblf32 = 0; } // d_out(204.8MB fp32) as scratch; head overwrites

  sniff_kernel<<<dim3(1), dim3(64), 0, stream>>>((const unsigned short*)t, flag);
  conv_kernel<<<dim3((CANON_N + 255) / 256), dim3(256), 0, stream>>>(
      flag, Whh, Wih, W1, W2, bhh, bih, b1, b2, canon);
  if (wbf)
    convw_kernel<<<dim3((NITEMS * HD / 4 + 255) / 256), dim3(256), 0, stream>>>(
        flag, Whead, wheadb);
  dt_kernel<<<dim3((B_SZ * S_LEN + 255) / 256), dim3(256), 0, stream>>>(t, flag, dtbuf);
  gitems_kernel<<<dim3(NPAD / 64, 3), dim3(256), 0, stream>>>(emb, canon, flag, tbl, tblf32);
  scan_kernel<<<dim3(64), dim3(512), 0, stream>>>(x, dtbuf, canon, tbl, tblf32, hstate);
  head_kernel<<<dim3(B_SZ / 64, (NITEMS + 255) / 256), dim3(256), 0, stream>>>(
      hstate, wheadb, Whead, bhead, flag, wbf, d_out);
}